// Round 2
// baseline (638.678 us; speedup 1.0000x reference)
//
#include <hip/hip_runtime.h>

namespace {

constexpr int T = 1024;
constexpr int B = 1024;
constexpr int L = 10;
constexpr int H = 10;
constexpr int NTHREADS = 256;      // 4 waves: w<3 -> layers 3w..3w+2, w3 -> layer 9
constexpr int U = 4;               // timesteps per interval
constexpr int NWIN = T / U;        // 256 windows
constexpr int NINT = NWIN + L - 1; // 265 intervals
constexpr int BH = B * H;
constexpr int ROW = 24;            // padded row (floats); 20 used (splat pairs)

using v2f = __attribute__((ext_vector_type(2))) float;
using v4f = __attribute__((ext_vector_type(4))) float;

__device__ __forceinline__ v2f v2fma(v2f a, v2f b, v2f c) {
    return __builtin_elementwise_fma(a, b, c);   // v_pk_fma_f32
}
__device__ __forceinline__ void pin2(v2f& v) { asm volatile("" : "+v"(v)); }
__device__ __forceinline__ float rcp_f(float x) { return __builtin_amdgcn_rcpf(x); }
// swap with adjacent lane (quad_perm [1,0,3,2]) - pure VALU, no LDS
__device__ __forceinline__ float dpp_swap1(float v) {
    return __int_as_float(__builtin_amdgcn_mov_dpp(__float_as_int(v), 0xB1, 0xF, 0xF, true));
}
__device__ __forceinline__ v2f lo2(v4f q) { return __builtin_shufflevector(q, q, 0, 1); }
__device__ __forceinline__ v2f hi2(v4f q) { return __builtin_shufflevector(q, q, 2, 3); }

__global__
__attribute__((amdgpu_flat_work_group_size(NTHREADS, NTHREADS)))
__attribute__((amdgpu_waves_per_eu(4)))   // cap VGPR at 128: need 4 waves/SIMD (16/CU)
void lstm_pipeline(const float* __restrict__ x,    // [T,B,H]
                   const float* __restrict__ hp,   // [L,B,H]
                   const float* __restrict__ cp,   // [L,B,H]
                   const float* __restrict__ Wih,  // [L,4H,H]
                   const float* __restrict__ Whh,  // [L,4H,H]
                   const float* __restrict__ bih,  // [L,4H]
                   const float* __restrict__ bhh,  // [L,4H]
                   float* __restrict__ out,        // [T,B,H]
                   float* __restrict__ hn,         // [L,B,H]
                   float* __restrict__ cn)         // [L,B,H]
{
    __shared__ __align__(16) float buf[2][U][L + 1][ROW];  // 8448 B, splat pairs
    __shared__ __align__(16) float hbuf[L][ROW];           //  960 B, splat pairs

    const int tid = threadIdx.x;
    const int wv = tid >> 6;
    const int ln = tid & 63;
    // item q in wave: 20 lanes per layer = 10 j x 2 gate-pairs (p). Pairs are
    // adjacent even/odd lanes (dpp quad_perm partner). Dup lanes repeat valid
    // items of the same wave -> identical values/addresses, benign.
    int q, l;
    if (wv < 3) { q = (ln < 60) ? ln : (ln - 8); l = 3 * wv + q / 20; }
    else        { q = ln % 20;  l = 9; }
    const int j = (q % 20) >> 1;
    const int p = q & 1;                 // 0: gates (i,f)  1: gates (g,o)
    const int b = blockIdx.x;
    const int boff = b * H + j;

    // ---- weights global -> registers, interleaved (row 2p, row 2p+1) ----
    v2f wipk[10], whpk[10], biasv;
    {
        const int r0 = (l * 4 + 2 * p) * H + j;       // flat row in [L*4H]
        const float* wi0 = Wih + (size_t)r0 * H;
        const float* wh0 = Whh + (size_t)r0 * H;
        #pragma unroll
        for (int i = 0; i < H; ++i) {
            wipk[i][0] = wi0[i]; wipk[i][1] = wi0[H * H + i];   // +H rows
            whpk[i][0] = wh0[i]; whpk[i][1] = wh0[H * H + i];
        }
        biasv[0] = bih[r0] + bhh[r0];
        biasv[1] = bih[r0 + H] + bhh[r0 + H];
    }
    #pragma unroll
    for (int i = 0; i < H; ++i) { pin2(wipk[i]); pin2(whpk[i]); }
    pin2(biasv);
    const float s0 = p ? 2.0f : -1.0f;   // exp scale for gate 2p (tanh uses +2x)

    float h = hp[(l * B + b) * H + j];
    float c = cp[(l * B + b) * H + j];
    { v2f hh; hh[0] = h; hh[1] = h; *(v2f*)&hbuf[l][2 * j] = hh; }

    const bool stager = (l == 0 && p == 0);
    float xcur[U];
    if (stager) {
        #pragma unroll
        for (int u = 0; u < U; ++u) {
            float xv = x[(size_t)u * BH + boff];
            v2f xx; xx[0] = xv; xx[1] = xv;
            *(v2f*)&buf[1][u][0][2 * j] = xx;          // window 0 (rp=1 first)
        }
        #pragma unroll
        for (int u = 0; u < U; ++u) xcur[u] = x[(size_t)(U + u) * BH + boff];
    }
    __syncthreads();

    auto interval = [&](int k, int wp, int rp) {
        const unsigned w = (unsigned)(k - l);
        if (w < (unsigned)NWIN) {
            // ---- phase 1: x-projections for all 4 timesteps ----
            v2f acc[U];
            #pragma unroll
            for (int u = 0; u < U; ++u) {
                const float* xr = &buf[rp][u][l][0];
                v4f q0 = *(const v4f*)(xr + 0);
                v4f q1 = *(const v4f*)(xr + 4);
                v4f q2 = *(const v4f*)(xr + 8);
                v4f q3 = *(const v4f*)(xr + 12);
                v4f q4 = *(const v4f*)(xr + 16);
                v2f z; z[0] = 0.0f; z[1] = 0.0f;
                v2f a  = v2fma(wipk[0], lo2(q0), biasv);
                v2f a2 = v2fma(wipk[1], hi2(q0), z);
                a  = v2fma(wipk[2], lo2(q1), a);
                a2 = v2fma(wipk[3], hi2(q1), a2);
                a  = v2fma(wipk[4], lo2(q2), a);
                a2 = v2fma(wipk[5], hi2(q2), a2);
                a  = v2fma(wipk[6], lo2(q3), a);
                a2 = v2fma(wipk[7], hi2(q3), a2);
                a  = v2fma(wipk[8], lo2(q4), a);
                a2 = v2fma(wipk[9], hi2(q4), a2);
                acc[u] = a + a2;
            }
            // ---- phase 2: serial recurrence ----
            float hv[U];
            #pragma unroll
            for (int u = 0; u < U; ++u) {
                const float* hr = &hbuf[l][0];
                v4f q0 = *(const v4f*)(hr + 0);
                v4f q1 = *(const v4f*)(hr + 4);
                v4f q2 = *(const v4f*)(hr + 8);
                v4f q3 = *(const v4f*)(hr + 12);
                v4f q4 = *(const v4f*)(hr + 16);
                v2f z; z[0] = 0.0f; z[1] = 0.0f;
                v2f a  = v2fma(whpk[0], lo2(q0), acc[u]);
                v2f a2 = v2fma(whpk[1], hi2(q0), z);
                a  = v2fma(whpk[2], lo2(q1), a);
                a2 = v2fma(whpk[3], hi2(q1), a2);
                a  = v2fma(whpk[4], lo2(q2), a);
                a2 = v2fma(whpk[5], hi2(q2), a2);
                a  = v2fma(whpk[6], lo2(q3), a);
                a2 = v2fma(whpk[7], hi2(q3), a2);
                a  = v2fma(whpk[8], lo2(q4), a);
                a2 = v2fma(whpk[9], hi2(q4), a2);
                v2f pre = a + a2;
                // two activations (same formulas as before -> same numerics)
                const float e0 = __expf(pre[0] * s0);     // sig(-x) / tanh(2x) core
                const float e1 = __expf(-pre[1]);         // always sigmoid
                const float r0 = rcp_f(1.0f + e0);
                const float r1 = rcp_f(1.0f + e1);
                // exchange with partner lane (other gate pair)
                const float x0 = dpp_swap1(r0);
                const float x1 = dpp_swap1(r1);
                const float ig = p ? x0 : r0;
                const float fg = p ? x1 : r1;
                const float og = p ? r1 : x1;
                const float gs = p ? r0 : x0;
                const float gg = fmaf(-2.0f, gs, 1.0f);   // tanh = 1 - 2*rcp(1+e^2x)
                c = fmaf(fg, c, ig * gg);
                const float th = 1.0f - 2.0f * rcp_f(1.0f + __expf(2.0f * c));
                h = og * th;
                v2f hh; hh[0] = h; hh[1] = h;             // splat pair
                *(v2f*)&hbuf[l][2 * j] = hh;              // same-wave readers at u+1
                *(v2f*)&buf[wp][u][l + 1][2 * j] = hh;    // l=9 -> pad row 10
                hv[u] = h;
            }
            if (l == L - 1 && p == 0) {                   // batched out-stores
                const int t0 = (int)w * U;
                #pragma unroll
                for (int u = 0; u < U; ++u)
                    out[(size_t)(t0 + u) * BH + boff] = hv[u];
            }
        }
        // Stage x window k+1, then issue loads for window k+2 (one ahead).
        if (stager && (k + 1) < NWIN) {
            #pragma unroll
            for (int u = 0; u < U; ++u) {
                v2f xx; xx[0] = xcur[u]; xx[1] = xcur[u];
                *(v2f*)&buf[wp][u][0][2 * j] = xx;
            }
            if ((k + 2) < NWIN) {
                #pragma unroll
                for (int u = 0; u < U; ++u)
                    xcur[u] = x[(size_t)((k + 2) * U + u) * BH + boff];
            }
        }
        __syncthreads();
    };

    for (int kk = 0; kk < NINT + 1; kk += 2) {   // literal parities
        interval(kk, 0, 1);
        interval(kk + 1, 1, 0);
    }

    hn[(l * B + b) * H + j] = h;   // both p lanes hold identical h,c
    cn[(l * B + b) * H + j] = c;
}

} // namespace

extern "C" void kernel_launch(void* const* d_in, const int* in_sizes, int n_in,
                              void* d_out, int out_size, void* d_ws, size_t ws_size,
                              hipStream_t stream) {
    (void)in_sizes; (void)n_in; (void)d_ws; (void)ws_size; (void)out_size;
    const float* x   = (const float*)d_in[0];
    const float* hp  = (const float*)d_in[1];
    const float* cp  = (const float*)d_in[2];
    const float* Wih = (const float*)d_in[3];
    const float* Whh = (const float*)d_in[4];
    const float* bih = (const float*)d_in[5];
    const float* bhh = (const float*)d_in[6];

    float* out = (float*)d_out;
    float* hn  = out + (size_t)T * B * H;
    float* cn  = hn + (size_t)L * B * H;

    lstm_pipeline<<<dim3(B), dim3(NTHREADS), 0, stream>>>(
        x, hp, cp, Wih, Whh, bih, bhh, out, hn, cn);
}